// Round 1
// baseline (1982.747 us; speedup 1.0000x reference)
//
#include <hip/hip_runtime.h>

#define B_  64
#define S_  128
#define H_  8
#define D_  64
#define HID 512
#define JT  32
#define PAD 65

// ---------------- Kernel 1: fused QKV projection GEMM (f32) ----------------
// A [8192,512] @ W [512,512] + bias -> C [8192,512]; blockIdx.z selects q/k/v.
__global__ __launch_bounds__(256) void qkv_gemm(
    const float* __restrict__ A,
    const float* __restrict__ Wq, const float* __restrict__ bq,
    const float* __restrict__ Wk, const float* __restrict__ bk,
    const float* __restrict__ Wv, const float* __restrict__ bv,
    float* __restrict__ Q, float* __restrict__ K, float* __restrict__ V)
{
    constexpr int BM = 128, BN = 128, BK = 16;
    const int z = blockIdx.z;
    const float* W    = (z == 0) ? Wq : (z == 1) ? Wk : Wv;
    const float* bias = (z == 0) ? bq : (z == 1) ? bk : bv;
    float* C          = (z == 0) ? Q  : (z == 1) ? K  : V;

    const int bm = blockIdx.y * BM;
    const int bn = blockIdx.x * BN;
    const int t  = threadIdx.x;

    __shared__ float As[BK][BM];
    __shared__ float Bs[BK][BN];

    const int tx = t & 15;    // 16 col groups
    const int ty = t >> 4;    // 16 row groups
    const int m0 = ty * 8;
    const int n0 = tx * 8;

    float acc[8][8] = {};

    for (int k0 = 0; k0 < HID; k0 += BK) {
        // A tile: 128x16 = 512 float4, transposed store into As[k][m]
        #pragma unroll
        for (int l = 0; l < 2; ++l) {
            int idx = t + l * 256;
            int row = idx >> 2;
            int c4  = (idx & 3) * 4;
            float4 a = *reinterpret_cast<const float4*>(&A[(size_t)(bm + row) * HID + k0 + c4]);
            As[c4 + 0][row] = a.x; As[c4 + 1][row] = a.y;
            As[c4 + 2][row] = a.z; As[c4 + 3][row] = a.w;
        }
        // B tile: 16x128 = 512 float4, direct
        #pragma unroll
        for (int l = 0; l < 2; ++l) {
            int idx = t + l * 256;
            int row = idx >> 5;
            int c4  = (idx & 31) * 4;
            *reinterpret_cast<float4*>(&Bs[row][c4]) =
                *reinterpret_cast<const float4*>(&W[(size_t)(k0 + row) * HID + bn + c4]);
        }
        __syncthreads();
        #pragma unroll
        for (int kk = 0; kk < BK; ++kk) {
            float a[8], b[8];
            *reinterpret_cast<float4*>(&a[0]) = *reinterpret_cast<const float4*>(&As[kk][m0]);
            *reinterpret_cast<float4*>(&a[4]) = *reinterpret_cast<const float4*>(&As[kk][m0 + 4]);
            *reinterpret_cast<float4*>(&b[0]) = *reinterpret_cast<const float4*>(&Bs[kk][n0]);
            *reinterpret_cast<float4*>(&b[4]) = *reinterpret_cast<const float4*>(&Bs[kk][n0 + 4]);
            #pragma unroll
            for (int i = 0; i < 8; ++i)
                #pragma unroll
                for (int j = 0; j < 8; ++j)
                    acc[i][j] += a[i] * b[j];
        }
        __syncthreads();
    }
    float bb[8];
    *reinterpret_cast<float4*>(&bb[0]) = *reinterpret_cast<const float4*>(&bias[bn + n0]);
    *reinterpret_cast<float4*>(&bb[4]) = *reinterpret_cast<const float4*>(&bias[bn + n0 + 4]);
    #pragma unroll
    for (int i = 0; i < 8; ++i) {
        float* crow = &C[(size_t)(bm + m0 + i) * HID + bn + n0];
        float4 o0 = make_float4(acc[i][0] + bb[0], acc[i][1] + bb[1],
                                acc[i][2] + bb[2], acc[i][3] + bb[3]);
        float4 o1 = make_float4(acc[i][4] + bb[4], acc[i][5] + bb[5],
                                acc[i][6] + bb[6], acc[i][7] + bb[7]);
        *reinterpret_cast<float4*>(crow)     = o0;
        *reinterpret_cast<float4*>(crow + 4) = o1;
    }
}

// ---------------- Kernel 2: fused structure-proj + attention ----------------
// One block per (b, i). j-tiled: proj sq/sk/sv -> scores -> relu/rowsum -> ctx.
__global__ __launch_bounds__(256) void attn_kernel(
    const float* __restrict__ Q, const float* __restrict__ K, const float* __restrict__ V,
    const float* __restrict__ st,    // [B,S,S,D]
    const float* __restrict__ mask,  // [B,1,S,S]
    const float* __restrict__ Wsq, const float* __restrict__ bsq,
    const float* __restrict__ Wsk, const float* __restrict__ bsk,
    const float* __restrict__ Wsv, const float* __restrict__ bsv,
    float* __restrict__ out)
{
    const int i = blockIdx.x;
    const int b = blockIdx.y;
    const int t = threadIdx.x;

    __shared__ float kk_s[H_ * D_];
    __shared__ float st_s[JT][PAD];
    __shared__ float sq_s[JT][PAD];
    __shared__ float sk_s[JT][PAD];
    __shared__ float sv_s[JT][PAD];
    __shared__ float p_s[H_][JT];
    __shared__ float rs_s[H_];

    {   // k[b,:,i,:] = one 512-float row in [B,S,H*D] layout
        const float* krow = &K[((size_t)b * S_ + i) * HID];
        kk_s[t]       = krow[t];
        kk_s[t + 256] = krow[t + 256];
        if (t < H_) rs_s[t] = 0.f;
    }
    float ctx0 = 0.f, ctx1 = 0.f;
    const int h_s = t >> 5, jj_s = t & 31;    // scores mapping: 8h x 32j
    const int hc  = t >> 6, dc   = t & 63;    // ctx mapping: h=hc and hc+4
    const int jp  = t >> 3, dg   = (t & 7) * 8; // proj mapping: 32j x 8 d-groups

    __syncthreads();

    for (int tile = 0; tile < S_ / JT; ++tile) {
        const int j0 = tile * JT;
        {   // structure tile [JT][64], contiguous 32KB/4
            const float* sp = &st[(((size_t)b * S_ + i) * S_ + j0) * D_];
            #pragma unroll
            for (int l = 0; l < 2; ++l) {
                int idx = (t + l * 256) * 4;
                float4 v4 = *reinterpret_cast<const float4*>(&sp[idx]);
                int row = idx >> 6, col = idx & 63;
                st_s[row][col + 0] = v4.x; st_s[row][col + 1] = v4.y;
                st_s[row][col + 2] = v4.z; st_s[row][col + 3] = v4.w;
            }
        }
        __syncthreads();
        {   // three 64x64 projections; W rows from L1
            const float* Ws[3]   = {Wsq, Wsk, Wsv};
            const float* bss[3]  = {bsq, bsk, bsv};
            float* outs[3] = {&sq_s[0][0], &sk_s[0][0], &sv_s[0][0]};
            #pragma unroll
            for (int p = 0; p < 3; ++p) {
                const float* W = Ws[p];
                float acc[8];
                *reinterpret_cast<float4*>(&acc[0]) = *reinterpret_cast<const float4*>(&bss[p][dg]);
                *reinterpret_cast<float4*>(&acc[4]) = *reinterpret_cast<const float4*>(&bss[p][dg + 4]);
                #pragma unroll 8
                for (int c = 0; c < D_; ++c) {
                    float s = st_s[jp][c];
                    float w[8];
                    *reinterpret_cast<float4*>(&w[0]) = *reinterpret_cast<const float4*>(&W[c * D_ + dg]);
                    *reinterpret_cast<float4*>(&w[4]) = *reinterpret_cast<const float4*>(&W[c * D_ + dg + 4]);
                    #pragma unroll
                    for (int e = 0; e < 8; ++e) acc[e] += s * w[e];
                }
                float* o = outs[p] + jp * PAD + dg;
                #pragma unroll
                for (int e = 0; e < 8; ++e) o[e] = acc[e];
            }
        }
        __syncthreads();
        {   // scores for (h_s, j0+jj_s): fused 4-term dot over d
            const int j = j0 + jj_s;
            const float* qrow = &Q[((size_t)b * S_ + j) * HID + h_s * D_];
            float s = 0.f;
            #pragma unroll 8
            for (int d4 = 0; d4 < D_; d4 += 4) {
                float4 q4 = *reinterpret_cast<const float4*>(&qrow[d4]);
                s += (kk_s[h_s * D_ + d4 + 0] + sk_s[jj_s][d4 + 0]) * (q4.x + sq_s[jj_s][d4 + 0]);
                s += (kk_s[h_s * D_ + d4 + 1] + sk_s[jj_s][d4 + 1]) * (q4.y + sq_s[jj_s][d4 + 1]);
                s += (kk_s[h_s * D_ + d4 + 2] + sk_s[jj_s][d4 + 2]) * (q4.z + sq_s[jj_s][d4 + 2]);
                s += (kk_s[h_s * D_ + d4 + 3] + sk_s[jj_s][d4 + 3]) * (q4.w + sq_s[jj_s][d4 + 3]);
            }
            s = s * 0.125f + mask[((size_t)b * S_ + i) * S_ + j];
            float p = fmaxf(s, 0.f);
            p_s[h_s][jj_s] = p;
            float r = p;
            #pragma unroll
            for (int off = 16; off >= 1; off >>= 1) r += __shfl_xor(r, off);
            if (jj_s == 0) rs_s[h_s] += r;
        }
        __syncthreads();
        {   // ctx accumulation: thread handles (hc, dc) and (hc+4, dc)
            const float* vbase = &V[((size_t)b * S_ + j0) * HID];
            #pragma unroll 8
            for (int jj = 0; jj < JT; ++jj) {
                float sv = sv_s[jj][dc];
                float p0 = p_s[hc][jj];
                float p1 = p_s[hc + 4][jj];
                ctx0 += p0 * (vbase[jj * HID + hc * D_ + dc] + sv);
                ctx1 += p1 * (vbase[jj * HID + (hc + 4) * D_ + dc] + sv);
            }
        }
        __syncthreads();
    }
    const float den0 = rs_s[hc] + 1.28e-10f;       // sum(p + 1e-12) = sum(p) + 128e-12
    const float den1 = rs_s[hc + 4] + 1.28e-10f;
    float* orow = &out[((size_t)b * S_ + i) * HID];
    orow[t]       = ctx0 / den0;
    orow[t + 256] = ctx1 / den1;
}

extern "C" void kernel_launch(void* const* d_in, const int* in_sizes, int n_in,
                              void* d_out, int out_size, void* d_ws, size_t ws_size,
                              hipStream_t stream) {
    const float* hidden = (const float*)d_in[0];
    const float* mask   = (const float*)d_in[1];
    const float* st     = (const float*)d_in[2];
    const float* Wq  = (const float*)d_in[3];
    const float* bq  = (const float*)d_in[4];
    const float* Wk  = (const float*)d_in[5];
    const float* bk  = (const float*)d_in[6];
    const float* Wv  = (const float*)d_in[7];
    const float* bv  = (const float*)d_in[8];
    const float* Wsq = (const float*)d_in[9];
    const float* bsq = (const float*)d_in[10];
    const float* Wsk = (const float*)d_in[11];
    const float* bsk = (const float*)d_in[12];
    const float* Wsv = (const float*)d_in[13];
    const float* bsv = (const float*)d_in[14];
    float* out = (float*)d_out;

    const size_t qkv_elems = (size_t)B_ * S_ * HID;  // 4,194,304
    float* qb = (float*)d_ws;
    float* kb = qb + qkv_elems;
    float* vb = kb + qkv_elems;

    qkv_gemm<<<dim3(HID / 128, (B_ * S_) / 128, 3), 256, 0, stream>>>(
        hidden, Wq, bq, Wk, bk, Wv, bv, qb, kb, vb);
    attn_kernel<<<dim3(S_, B_), 256, 0, stream>>>(
        qb, kb, vb, st, mask, Wsq, bsq, Wsk, bsk, Wsv, bsv, out);
}

// Round 2
// 470.342 us; speedup vs baseline: 4.2155x; 4.2155x over previous
//
#include <hip/hip_runtime.h>

#define B_  64
#define S_  128
#define H_  8
#define D_  64
#define HID 512

typedef short short8 __attribute__((ext_vector_type(8)));
typedef float f32x4 __attribute__((ext_vector_type(4)));

__device__ __forceinline__ float bf2f(unsigned short h) {
    union { unsigned int u; float f; } v; v.u = (unsigned int)h << 16; return v.f;
}
__device__ __forceinline__ unsigned short f2bf(float f) {
    union { float f; unsigned int u; } v; v.f = f;
    unsigned int r = v.u + 0x7fffu + ((v.u >> 16) & 1u);
    return (unsigned short)(r >> 16);
}

// ---- transpose f32 [dim][dim] (in,out) -> bf16 [dim][dim] (out,in); z picks weight ----
__global__ __launch_bounds__(256) void wtrans(const float* __restrict__ s0,
                                              const float* __restrict__ s1,
                                              const float* __restrict__ s2,
                                              unsigned short* __restrict__ dst0, int dim)
{
    const float* srcs[3] = {s0, s1, s2};
    const float* src = srcs[blockIdx.z];
    unsigned short* dst = dst0 + (size_t)blockIdx.z * dim * dim;
    __shared__ float tile[32][33];
    const int tx = threadIdx.x & 31, ty = threadIdx.x >> 5;
    const int k0 = blockIdx.x * 32, n0 = blockIdx.y * 32;
    #pragma unroll
    for (int r = 0; r < 4; ++r) {
        int row = ty + r * 8;
        tile[row][tx] = src[(size_t)(k0 + row) * dim + n0 + tx];
    }
    __syncthreads();
    #pragma unroll
    for (int r = 0; r < 4; ++r) {
        int row = ty + r * 8;
        dst[(size_t)(n0 + row) * dim + k0 + tx] = f2bf(tile[tx][row]);
    }
}

// ---- QKV projection: bf16 MFMA GEMM, emits head-major Q/K bf16 and V bf16 ----
__global__ __launch_bounds__(256) void qkv_mfma(
    const float* __restrict__ hidden,
    const unsigned short* __restrict__ wt,   // [3][512][512] bf16 (out,in)
    const float* __restrict__ bq, const float* __restrict__ bk, const float* __restrict__ bv,
    unsigned short* __restrict__ Qb,   // [B][H][S][D]
    unsigned short* __restrict__ Kb,   // [B][H][S][D]
    unsigned short* __restrict__ Vb)   // [B*S][512]
{
    const int z = blockIdx.z;
    const unsigned short* W = wt + (size_t)z * HID * HID;
    const float* bias = (z == 0) ? bq : (z == 1) ? bk : bv;
    const int bm = blockIdx.y * 128, bn = blockIdx.x * 128;
    const int t = threadIdx.x, lane = t & 63, w = t >> 6, grp = lane >> 4, l15 = lane & 15;

    __shared__ unsigned short a_s[128 * 72];
    __shared__ unsigned short b_s[128 * 72];

    f32x4 acc[2][8];
    #pragma unroll
    for (int i = 0; i < 2; ++i)
        #pragma unroll
        for (int j = 0; j < 8; ++j) acc[i][j] = (f32x4){0.f, 0.f, 0.f, 0.f};

    for (int k0 = 0; k0 < HID; k0 += 64) {
        #pragma unroll
        for (int it = 0; it < 8; ++it) {             // A: 128x64 f32 -> bf16
            int idx = t + it * 256;
            int row = idx >> 4, c = idx & 15;
            float4 v4 = *reinterpret_cast<const float4*>(&hidden[(size_t)(bm + row) * HID + k0 + c * 4]);
            ushort4 o = {f2bf(v4.x), f2bf(v4.y), f2bf(v4.z), f2bf(v4.w)};
            *reinterpret_cast<ushort4*>(&a_s[row * 72 + c * 4]) = o;
        }
        #pragma unroll
        for (int it = 0; it < 4; ++it) {             // B: 128 n-rows x 64 k bf16
            int idx = t + it * 256;
            int row = idx >> 3, c = idx & 7;
            *reinterpret_cast<short8*>(&b_s[row * 72 + c * 8]) =
                *reinterpret_cast<const short8*>(&W[(size_t)(bn + row) * HID + k0 + c * 8]);
        }
        __syncthreads();
        short8 af[2][2];
        #pragma unroll
        for (int mt = 0; mt < 2; ++mt)
            #pragma unroll
            for (int kk = 0; kk < 2; ++kk)
                af[mt][kk] = *reinterpret_cast<const short8*>(&a_s[(w * 32 + mt * 16 + l15) * 72 + kk * 32 + grp * 8]);
        #pragma unroll
        for (int nt = 0; nt < 8; ++nt) {
            short8 b0 = *reinterpret_cast<const short8*>(&b_s[(nt * 16 + l15) * 72 + grp * 8]);
            short8 b1 = *reinterpret_cast<const short8*>(&b_s[(nt * 16 + l15) * 72 + 32 + grp * 8]);
            #pragma unroll
            for (int mt = 0; mt < 2; ++mt) {
                acc[mt][nt] = __builtin_amdgcn_mfma_f32_16x16x32_bf16(af[mt][0], b0, acc[mt][nt], 0, 0, 0);
                acc[mt][nt] = __builtin_amdgcn_mfma_f32_16x16x32_bf16(af[mt][1], b1, acc[mt][nt], 0, 0, 0);
            }
        }
        __syncthreads();
    }
    unsigned short* dstqk = (z == 0) ? Qb : Kb;
    #pragma unroll
    for (int nt = 0; nt < 8; ++nt) {
        int col = bn + nt * 16 + l15;
        float bval = bias[col];
        #pragma unroll
        for (int mt = 0; mt < 2; ++mt) {
            #pragma unroll
            for (int r = 0; r < 4; ++r) {
                int row = bm + w * 32 + mt * 16 + grp * 4 + r;
                unsigned short val = f2bf(acc[mt][nt][r] + bval);
                if (z == 2) {
                    Vb[(size_t)row * HID + col] = val;
                } else {
                    int bb = row >> 7, jj = row & 127, hh = col >> 6, dd = col & 63;
                    dstqk[(((size_t)bb * H_ + hh) * S_ + jj) * D_ + dd] = val;
                }
            }
        }
    }
}

// ---- scores0[b,h,i,j] = sum_d K[b,h,i,d] * Q[b,h,j,d] ----
__global__ __launch_bounds__(256) void kq_gemm(
    const unsigned short* __restrict__ Kb, const unsigned short* __restrict__ Qb,
    float* __restrict__ sc0)
{
    const int bh = blockIdx.x;
    const int t = threadIdx.x, lane = t & 63, w = t >> 6, grp = lane >> 4, l15 = lane & 15;
    const unsigned short* Kp = Kb + (size_t)bh * S_ * D_;
    const unsigned short* Qp = Qb + (size_t)bh * S_ * D_;
    float* outp = sc0 + (size_t)bh * S_ * S_;
    short8 af[2][2];
    #pragma unroll
    for (int mt = 0; mt < 2; ++mt)
        #pragma unroll
        for (int kk = 0; kk < 2; ++kk)
            af[mt][kk] = *reinterpret_cast<const short8*>(&Kp[(size_t)(w * 32 + mt * 16 + l15) * D_ + kk * 32 + grp * 8]);
    #pragma unroll
    for (int nt = 0; nt < 8; ++nt) {
        short8 b0 = *reinterpret_cast<const short8*>(&Qp[(size_t)(nt * 16 + l15) * D_ + grp * 8]);
        short8 b1 = *reinterpret_cast<const short8*>(&Qp[(size_t)(nt * 16 + l15) * D_ + 32 + grp * 8]);
        #pragma unroll
        for (int mt = 0; mt < 2; ++mt) {
            f32x4 a = {0.f, 0.f, 0.f, 0.f};
            a = __builtin_amdgcn_mfma_f32_16x16x32_bf16(af[mt][0], b0, a, 0, 0, 0);
            a = __builtin_amdgcn_mfma_f32_16x16x32_bf16(af[mt][1], b1, a, 0, 0, 0);
            #pragma unroll
            for (int r = 0; r < 4; ++r)
                outp[(size_t)(w * 32 + mt * 16 + grp * 4 + r) * S_ + nt * 16 + l15] = a[r];
        }
    }
}

// ---- fused structure-proj (MFMA) + scores + ctx, one block per (b,i) ----
__global__ __launch_bounds__(256) void attn2(
    const unsigned short* __restrict__ Qb, const unsigned short* __restrict__ Kb,
    const unsigned short* __restrict__ Vb,
    const float* __restrict__ sc0,
    const float* __restrict__ st, const float* __restrict__ mask,
    const unsigned short* __restrict__ wtS,   // [3][64][64] (out,in)
    const float* __restrict__ bsq, const float* __restrict__ bsk, const float* __restrict__ bsv,
    float* __restrict__ out)
{
    const int i = blockIdx.x, b = blockIdx.y;
    const int t = threadIdx.x, lane = t & 63, w = t >> 6, grp = lane >> 4, l15 = lane & 15;

    __shared__ __align__(16) unsigned char smem[76096];
    unsigned short* st_s = (unsigned short*)smem;             // [128][72] bf16 (dead after proj)
    float*          scf  = (float*)smem;                      // [8][128] f32 (ksq, then p) - overlays st
    unsigned short* sq_s = (unsigned short*)(smem + 18432);   // [128][72]
    unsigned short* sk_s = (unsigned short*)(smem + 36864);
    unsigned short* sv_s = (unsigned short*)(smem + 55296);
    unsigned short* k_s  = (unsigned short*)(smem + 73728);   // [16][72], rows 8..15 zero
    float*          rsp  = (float*)(smem + 76032);            // [4][4]

    // ---- stage: st -> bf16 LDS; k_i -> k_s ----
    {
        const float* stp = st + ((size_t)b * S_ + i) * S_ * D_;
        #pragma unroll
        for (int it = 0; it < 8; ++it) {
            int idx = t + it * 256;                 // 2048 float4 chunks
            int row = idx >> 4, c = idx & 15;
            float4 v4 = *reinterpret_cast<const float4*>(stp + (size_t)idx * 4);
            ushort4 o = {f2bf(v4.x), f2bf(v4.y), f2bf(v4.z), f2bf(v4.w)};
            *reinterpret_cast<ushort4*>(&st_s[row * 72 + c * 4]) = o;
        }
        if (t < 64) {
            int h = t >> 3, c = t & 7;
            *reinterpret_cast<short8*>(&k_s[h * 72 + c * 8]) =
                *reinterpret_cast<const short8*>(&Kb[(((size_t)b * H_ + h) * S_ + i) * D_ + c * 8]);
        } else if (t < 128) {
            int h = 8 + ((t - 64) >> 3), c = t & 7;
            short8 zz = {0, 0, 0, 0, 0, 0, 0, 0};
            *reinterpret_cast<short8*>(&k_s[h * 72 + c * 8]) = zz;
        }
    }
    __syncthreads();

    // ---- projections sq/sk/sv = st @ Ws + bs (MFMA) ----
    {
        short8 af[2][2];
        #pragma unroll
        for (int mt = 0; mt < 2; ++mt)
            #pragma unroll
            for (int kk = 0; kk < 2; ++kk)
                af[mt][kk] = *reinterpret_cast<const short8*>(&st_s[(w * 32 + mt * 16 + l15) * 72 + kk * 32 + grp * 8]);
        const float* bss[3] = {bsq, bsk, bsv};
        unsigned short* outs[3] = {sq_s, sk_s, sv_s};
        #pragma unroll
        for (int p = 0; p < 3; ++p) {
            const unsigned short* Wp = wtS + (size_t)p * 64 * 64;
            #pragma unroll
            for (int nt = 0; nt < 4; ++nt) {
                short8 b0 = *reinterpret_cast<const short8*>(&Wp[(size_t)(nt * 16 + l15) * 64 + grp * 8]);
                short8 b1 = *reinterpret_cast<const short8*>(&Wp[(size_t)(nt * 16 + l15) * 64 + 32 + grp * 8]);
                float bval = bss[p][nt * 16 + l15];
                #pragma unroll
                for (int mt = 0; mt < 2; ++mt) {
                    f32x4 a = {0.f, 0.f, 0.f, 0.f};
                    a = __builtin_amdgcn_mfma_f32_16x16x32_bf16(af[mt][0], b0, a, 0, 0, 0);
                    a = __builtin_amdgcn_mfma_f32_16x16x32_bf16(af[mt][1], b1, a, 0, 0, 0);
                    #pragma unroll
                    for (int r = 0; r < 4; ++r)
                        outs[p][(w * 32 + mt * 16 + grp * 4 + r) * 72 + nt * 16 + l15] = f2bf(a[r] + bval);
                }
            }
        }
    }
    __syncthreads();

    // ---- ksq[h,j] = sum_d k_i[h,d] * sq[j,d]  (MFMA, M=8 padded to 16) ----
    {
        short8 ka0 = *reinterpret_cast<const short8*>(&k_s[l15 * 72 + grp * 8]);
        short8 ka1 = *reinterpret_cast<const short8*>(&k_s[l15 * 72 + 32 + grp * 8]);
        #pragma unroll
        for (int nt = 0; nt < 2; ++nt) {
            int j0 = w * 32 + nt * 16;
            short8 b0 = *reinterpret_cast<const short8*>(&sq_s[(j0 + l15) * 72 + grp * 8]);
            short8 b1 = *reinterpret_cast<const short8*>(&sq_s[(j0 + l15) * 72 + 32 + grp * 8]);
            f32x4 a = {0.f, 0.f, 0.f, 0.f};
            a = __builtin_amdgcn_mfma_f32_16x16x32_bf16(ka0, b0, a, 0, 0, 0);
            a = __builtin_amdgcn_mfma_f32_16x16x32_bf16(ka1, b1, a, 0, 0, 0);
            if (grp < 2) {
                #pragma unroll
                for (int r = 0; r < 4; ++r)
                    scf[(grp * 4 + r) * 128 + j0 + l15] = a[r];
            }
        }
    }
    __syncthreads();

    // ---- scores: s = (kq + ksq + qsk + sksq)/8 + mask; p = relu; rowsum ----
    const int jj = (w & 1) * 64 + lane;
    const int hg = w >> 1;
    {
        const unsigned short* skr = &sk_s[jj * 72];
        const unsigned short* sqr = &sq_s[jj * 72];
        const unsigned short* qp = Qb + (((size_t)b * H_ + hg * 4) * S_ + jj) * D_;
        float a0 = 0.f, a1 = 0.f, a2 = 0.f, a3 = 0.f, ss = 0.f;
        #pragma unroll
        for (int c = 0; c < 8; ++c) {
            short8 sk8 = *reinterpret_cast<const short8*>(&skr[c * 8]);
            short8 sq8 = *reinterpret_cast<const short8*>(&sqr[c * 8]);
            short8 q0 = *reinterpret_cast<const short8*>(&qp[c * 8]);
            short8 q1 = *reinterpret_cast<const short8*>(&qp[S_ * D_ + c * 8]);
            short8 q2 = *reinterpret_cast<const short8*>(&qp[2 * S_ * D_ + c * 8]);
            short8 q3 = *reinterpret_cast<const short8*>(&qp[3 * S_ * D_ + c * 8]);
            #pragma unroll
            for (int e = 0; e < 8; ++e) {
                float skf = bf2f((unsigned short)sk8[e]);
                float sqf = bf2f((unsigned short)sq8[e]);
                a0 += bf2f((unsigned short)q0[e]) * skf;
                a1 += bf2f((unsigned short)q1[e]) * skf;
                a2 += bf2f((unsigned short)q2[e]) * skf;
                a3 += bf2f((unsigned short)q3[e]) * skf;
                ss += skf * sqf;
            }
        }
        float mv = mask[((size_t)b * S_ + i) * S_ + jj];
        const float* s0p = sc0 + (((size_t)b * H_ + hg * 4) * S_ + i) * S_ + jj;
        float qsk[4] = {a0, a1, a2, a3};
        float pv[4];
        #pragma unroll
        for (int hh = 0; hh < 4; ++hh) {
            int h = hg * 4 + hh;
            float kqv = s0p[(size_t)hh * S_ * S_];
            float ksqv = scf[h * 128 + jj];
            float s = (kqv + ksqv + qsk[hh] + ss) * 0.125f + mv;
            pv[hh] = fmaxf(s, 0.f);
        }
        #pragma unroll
        for (int hh = 0; hh < 4; ++hh) {
            scf[(hg * 4 + hh) * 128 + jj] = pv[hh];   // own (h,jj): safe overwrite
            float r = pv[hh];
            #pragma unroll
            for (int off = 1; off < 64; off <<= 1) r += __shfl_xor(r, off);
            if (lane == 0) rsp[w * 4 + hh] = r;
        }
    }
    __syncthreads();

    // ---- ctx[h,d] = sum_j p[h,j] * (v[j,h,d] + sv[j,d]); normalize; write ----
    {
        const int hc = t >> 6, dc = t & 63;
        const int h0 = hc, h1 = hc + 4;
        float den0 = rsp[((h0 >> 2) * 2) * 4 + (h0 & 3)] + rsp[((h0 >> 2) * 2 + 1) * 4 + (h0 & 3)] + 1.28e-10f;
        float den1 = rsp[((h1 >> 2) * 2) * 4 + (h1 & 3)] + rsp[((h1 >> 2) * 2 + 1) * 4 + (h1 & 3)] + 1.28e-10f;
        const unsigned short* vp = Vb + (size_t)b * S_ * HID;
        float c0 = 0.f, c1 = 0.f;
        #pragma unroll 4
        for (int j = 0; j < S_; ++j) {
            float p0 = scf[h0 * 128 + j];
            float p1 = scf[h1 * 128 + j];
            float svv = bf2f(sv_s[j * 72 + dc]);
            float v0 = bf2f(vp[(size_t)j * HID + h0 * 64 + dc]);
            float v1 = bf2f(vp[(size_t)j * HID + h1 * 64 + dc]);
            c0 += p0 * (v0 + svv);
            c1 += p1 * (v1 + svv);
        }
        float* orow = out + ((size_t)b * S_ + i) * HID;
        orow[t]       = c0 / den0;
        orow[t + 256] = c1 / den1;
    }
}

extern "C" void kernel_launch(void* const* d_in, const int* in_sizes, int n_in,
                              void* d_out, int out_size, void* d_ws, size_t ws_size,
                              hipStream_t stream) {
    const float* hidden = (const float*)d_in[0];
    const float* mask   = (const float*)d_in[1];
    const float* st     = (const float*)d_in[2];
    const float* Wq  = (const float*)d_in[3];
    const float* bq  = (const float*)d_in[4];
    const float* Wk  = (const float*)d_in[5];
    const float* bk  = (const float*)d_in[6];
    const float* Wv  = (const float*)d_in[7];
    const float* bv  = (const float*)d_in[8];
    const float* Wsq = (const float*)d_in[9];
    const float* bsq = (const float*)d_in[10];
    const float* Wsk = (const float*)d_in[11];
    const float* bsk = (const float*)d_in[12];
    const float* Wsv = (const float*)d_in[13];
    const float* bsv = (const float*)d_in[14];
    float* out = (float*)d_out;

    unsigned char* ws = (unsigned char*)d_ws;
    unsigned short* wtB = (unsigned short*)(ws);                 // 3*512*512*2 = 1572864
    unsigned short* wtS = (unsigned short*)(ws + 1572864);       // 3*64*64*2   = 24576
    unsigned short* Qb  = (unsigned short*)(ws + 1597440);       // 8388608
    unsigned short* Kb  = (unsigned short*)(ws + 9986048);       // 8388608
    unsigned short* Vb  = (unsigned short*)(ws + 18374656);      // 8388608
    float*          sc0 = (float*)(ws + 26763264);               // 33554432 -> end 60317696

    wtrans<<<dim3(16, 16, 3), 256, 0, stream>>>(Wq, Wk, Wv, wtB, 512);
    wtrans<<<dim3(2, 2, 3), 256, 0, stream>>>(Wsq, Wsk, Wsv, wtS, 64);
    qkv_mfma<<<dim3(4, 64, 3), 256, 0, stream>>>(hidden, wtB, bq, bk, bv, Qb, Kb, Vb);
    kq_gemm<<<dim3(512), 256, 0, stream>>>(Kb, Qb, sc0);
    attn2<<<dim3(S_, B_), 256, 0, stream>>>(Qb, Kb, Vb, sc0, st, mask, wtS, bsq, bsk, bsv, out);
}